// Round 10
// baseline (119.809 us; speedup 1.0000x reference)
//
#include <hip/hip_runtime.h>

// STFT: x[16, 262144] fp32, Hann 2048, hop 512, reflect pad 1024.
// Output: real[16,1025,513] ++ imag[16,1025,513], fp32.
//
// Round 17: 8-blocks/CU probe (pre-committed in R16). R16's fusion was flat
// (43 vs 42.7): phase instruction count is not the critical path; the
// barrier-serialized phase chain is. Only other resident blocks can overlap
// it, and R9 measured the lever (2->4 blocks/CU = 52->49). This round:
//  - 256 threads, 1 packed FFT (frames f0, f0+1), LDS float2 z[2113] =
//    16.9 KB -> 8 blocks/CU (135 KB, 32 waves: both CU limits exactly met),
//    8 independent barrier domains per CU. __launch_bounds__(256,8).
//  - Grid 4112 = 16 tail (first) + 4096 main. XCD swizzle: 16 consecutive g
//    (= 32 frames = one 128 B output-line span) share an XCD in adjacent
//    dispatch slots so 8 B row chunks still L2-merge (R8/R9 mechanism).
//  - Per-thread phase work unchanged from R16: float4 interior loader
//    (refl dead for g in [1,254]), 1 octet item per trip, 2 register-quad
//    items with v2/v3 stash, fused epilogue (4 rows/thread, 8 B stores).

#define N_FFT   2048
#define LOG2N   11
#define HOP     512
#define PADL    1024
#define NBINS   1025
#define NFRAMES 513
#define NBATCH  16
#define TLEN    262144

#define HALF_OUT ((size_t)NBATCH * NBINS * NFRAMES)   // 8,413,200 floats per plane

typedef float f2_t __attribute__((ext_vector_type(2)));
typedef f2_t uf2 __attribute__((aligned(4)));         // 4B-aligned dwordx2

__device__ __forceinline__ int pidx(int a) { return a + (a >> 5); }

__device__ __forceinline__ int refl(int j) {
    if (j < 0)          j = -j;
    else if (j >= TLEN) j = 2 * TLEN - 2 - j;
    return j;
}

__device__ __forceinline__ int brev11(int n) {
    return (int)(__brev((unsigned)n) >> 21);
}

__device__ __forceinline__ float2 cmul(float2 a, float2 w) {
    return make_float2(fmaf(a.x, w.x, -a.y * w.y), fmaf(a.x, w.y, a.y * w.x));
}
__device__ __forceinline__ float2 cadd(float2 a, float2 b) {
    return make_float2(a.x + b.x, a.y + b.y);
}
__device__ __forceinline__ float2 csub(float2 a, float2 b) {
    return make_float2(a.x - b.x, a.y - b.y);
}
__device__ __forceinline__ float2 csqr(float2 w) {
    return make_float2(fmaf(w.x, w.x, -w.y * w.y), 2.0f * w.x * w.y);
}

// Three DIT stages (halves H, 2H, 4H) on points base + m*H, m=0..7, in registers.
template <int H, int L2H>
__device__ __forceinline__ void octet_pass(float2* __restrict__ zc, int q) {
    const int p    = q & (H - 1);
    const int base = ((q >> L2H) << (L2H + 3)) + p;
    int ia[8];
#pragma unroll
    for (int m = 0; m < 8; ++m) ia[m] = pidx(base + m * H);
    float2 v0 = zc[ia[0]], v1 = zc[ia[1]], v2 = zc[ia[2]], v3 = zc[ia[3]];
    float2 v4 = zc[ia[4]], v5 = zc[ia[5]], v6 = zc[ia[6]], v7 = zc[ia[7]];

    float2 w1, w2, w3;
    if (H == 1) {
        w3 = make_float2(1.0f, 0.0f); w2 = w3; w1 = w3;   // p==0 always
    } else {
        float s, c;
        __sincosf((float)p * (-3.14159265358979323846f / (4.0f * (float)H)), &s, &c);
        w3 = make_float2(c, s);
        w2 = csqr(w3);
        w1 = csqr(w2);
    }

    float2 t;
    // stage A (half=H): pairs (0,1)(2,3)(4,5)(6,7), all twiddle w1
    t = cmul(v1, w1); v1 = csub(v0, t); v0 = cadd(v0, t);
    t = cmul(v3, w1); v3 = csub(v2, t); v2 = cadd(v2, t);
    t = cmul(v5, w1); v5 = csub(v4, t); v4 = cadd(v4, t);
    t = cmul(v7, w1); v7 = csub(v6, t); v6 = cadd(v6, t);
    // stage B (half=2H): pairs (0,2)(4,6) w2 ; (1,3)(5,7) -i*w2
    const float2 w2m = make_float2(w2.y, -w2.x);
    t = cmul(v2, w2);  v2 = csub(v0, t); v0 = cadd(v0, t);
    t = cmul(v3, w2m); v3 = csub(v1, t); v1 = cadd(v1, t);
    t = cmul(v6, w2);  v6 = csub(v4, t); v4 = cadd(v4, t);
    t = cmul(v7, w2m); v7 = csub(v5, t); v5 = cadd(v5, t);
    // stage C (half=4H): pairs (0,4) w3 ; (1,5) w3*e^{-i pi/4} ; (2,6) -i*w3 ; (3,7) -i*w3*e^{-i pi/4}
    const float R = 0.70710678118654752f;
    const float2 w3o  = make_float2((w3.x + w3.y) * R, (w3.y - w3.x) * R);
    const float2 w3m  = make_float2(w3.y, -w3.x);
    const float2 w3mo = make_float2(w3o.y, -w3o.x);
    t = cmul(v4, w3);   v4 = csub(v0, t); v0 = cadd(v0, t);
    t = cmul(v5, w3o);  v5 = csub(v1, t); v1 = cadd(v1, t);
    t = cmul(v6, w3m);  v6 = csub(v2, t); v2 = cadd(v2, t);
    t = cmul(v7, w3mo); v7 = csub(v3, t); v3 = cadd(v3, t);

    zc[ia[0]] = v0; zc[ia[1]] = v1; zc[ia[2]] = v2; zc[ia[3]] = v3;
    zc[ia[4]] = v4; zc[ia[5]] = v5; zc[ia[6]] = v6; zc[ia[7]] = v7;
}

// Radix-4 quad item (stages 10-11, h=512), twiddles precomputed by caller.
// (Tail path only.)
__device__ __forceinline__ void quad_core(float2* __restrict__ zc, int p,
                                          float2 w1, float2 w2, float2 w2m) {
    const int i0 = pidx(p), i1 = pidx(p + 512), i2 = pidx(p + 1024), i3 = pidx(p + 1536);
    float2 v0 = zc[i0], v1 = zc[i1], v2 = zc[i2], v3 = zc[i3];
    float2 t;
    t = cmul(v1, w1); v1 = csub(v0, t); v0 = cadd(v0, t);
    t = cmul(v3, w1); v3 = csub(v2, t); v2 = cadd(v2, t);
    t = cmul(v2, w2);  v2 = csub(v0, t); v0 = cadd(v0, t);
    t = cmul(v3, w2m); v3 = csub(v1, t); v1 = cadd(v1, t);
    zc[i0] = v0; zc[i1] = v1; zc[i2] = v2; zc[i3] = v3;
}

// One output row (2 frames) from a zk/zr pair.
__device__ __forceinline__ void store_row2(float* __restrict__ pr,
                                           float* __restrict__ pi,
                                           float2 zk, float2 zr) {
    uf2 re, im;
    re.x = 0.5f * (zk.x + zr.x);   // even frame re
    re.y = 0.5f * (zk.y + zr.y);   // odd frame re
    im.x = 0.5f * (zk.y - zr.y);   // even frame im
    im.y = 0.5f * (zr.x - zk.x);   // odd frame im
    *reinterpret_cast<uf2*>(pr) = re;
    *reinterpret_cast<uf2*>(pi) = im;
}

__global__ __launch_bounds__(256, 8) void stft_one(
    const float* __restrict__ x,
    const float* __restrict__ window,
    float* __restrict__ out)
{
    __shared__ float2 z[2113];        // 16,904 B -> 8 blocks/CU

    const int d   = blockIdx.x;
    const int tid = threadIdx.x;
    float* __restrict__ outr = out;
    float* __restrict__ outi = out + HALF_OUT;

    // ---------------- tail blocks: frame 512 of batch d, run first ----------
    if (d < NBATCH) {
        const int b = d;
        const float* xb = x + (size_t)b * TLEN;
        const int a0 = 512 * HOP - PADL;
#pragma unroll
        for (int it = 0; it < 8; ++it) {
            const int n = tid + it * 256;
            const float w  = window[n];
            const float va = xb[refl(a0 + n)] * w;
            const float vb = xb[refl(a0 + HOP + n)] * w;   // phantom frame, unused
            z[pidx(brev11(n))] = make_float2(va, vb);
        }
        __syncthreads();
        octet_pass<1, 0>(z, tid);  __syncthreads();
        octet_pass<8, 3>(z, tid);  __syncthreads();
        octet_pass<64, 6>(z, tid); __syncthreads();
#pragma unroll
        for (int it = 0; it < 2; ++it) {
            const int p = tid + it * 256;
            float s, cc;
            __sincosf((float)p * (-3.14159265358979323846f / 1024.0f), &s, &cc);
            const float2 w2  = make_float2(cc, s);
            const float2 w1  = csqr(w2);
            const float2 w2m = make_float2(w2.y, -w2.x);
            quad_core(z, p, w1, w2, w2m);
        }
        __syncthreads();
        for (int k = tid; k < NBINS; k += 256) {
            const int km = (N_FFT - k) & (N_FFT - 1);
            const float2 zk = z[pidx(k)];
            const float2 zr = z[pidx(km)];
            const size_t o = ((size_t)b * NBINS + (size_t)k) * NFRAMES + 512;
            outr[o] = 0.5f * (zk.x + zr.x);
            outi[o] = 0.5f * (zk.y - zr.y);
        }
        return;
    }

    // ---------------- main blocks ----------------
    // XCD swizzle: groups of 16 consecutive g (one 128 B output-line span,
    // 32 frames) get ids differing by 8 (same XCD) in adjacent slots.
    const int m    = d - NBATCH;                  // [0,4096)
    const int xcd  = m & 7;
    const int slot = m >> 3;                      // [0,512)
    const int G    = (slot >> 4) * 8 + xcd;       // group id [0,256)
    const int L    = G * 16 + (slot & 15);        // logical block [0,4096)
    const int b    = L >> 8;                      // [0,16)
    const int g    = L & 255;                     // [0,256)
    const int f0   = g * 2;

    const float* xb = x + (size_t)b * TLEN;
    const int a0    = f0 * HOP - PADL;            // = 1024*(g-1)

    // ---- load 2 windowed frames (1 plane), bit-reversed ----
    if (g >= 1 && g <= 254) {
        // interior: refl() dead (span [1024(g-1), 1024g+1535] in bounds).
#pragma unroll
        for (int it = 0; it < 2; ++it) {
            const int j  = tid + it * 256;        // [0,512)
            const int n0 = j << 2;
            const float4 w4 = *reinterpret_cast<const float4*>(&window[n0]);
            const float4 a4 = *reinterpret_cast<const float4*>(&xb[a0 + n0]);
            const float4 b4 = *reinterpret_cast<const float4*>(&xb[a0 + HOP + n0]);
            const int r0 = (int)(__brev((unsigned)j) >> 23);   // brev9(j)
            // brev11(4j+u) = brev9(j) + {0,1024,512,1536}[u]
            z[pidx(r0)]        = make_float2(a4.x * w4.x, b4.x * w4.x);
            z[pidx(r0 + 1024)] = make_float2(a4.y * w4.y, b4.y * w4.y);
            z[pidx(r0 + 512)]  = make_float2(a4.z * w4.z, b4.z * w4.z);
            z[pidx(r0 + 1536)] = make_float2(a4.w * w4.w, b4.w * w4.w);
        }
    } else {
        // edge blocks (g==0, g==255): scalar refl path
#pragma unroll
        for (int it = 0; it < 8; ++it) {
            const int n = tid + it * 256;
            const float w  = window[n];
            const float va = xb[refl(a0 + n)] * w;
            const float vb = xb[refl(a0 + HOP + n)] * w;
            z[pidx(brev11(n))] = make_float2(va, vb);
        }
    }
    __syncthreads();

    // ---- stages 1-9: three radix-8 register trips (1 item each) ----
    octet_pass<1, 0>(z, tid);  __syncthreads();
    octet_pass<8, 3>(z, tid);  __syncthreads();
    octet_pass<64, 6>(z, tid); __syncthreads();

    // ---- stages 10-11 in registers (items p=tid, p=tid+256); stash v2/v3 ----
    float2 V0[2], V1[2], V2[2];
#pragma unroll
    for (int itq = 0; itq < 2; ++itq) {
        const int p = tid + itq * 256;
        float s, cc;
        __sincosf((float)p * (-3.14159265358979323846f / 1024.0f), &s, &cc);
        const float2 w2  = make_float2(cc, s);    // exp(-i*pi*p/1024)
        const float2 w1  = csqr(w2);              // exp(-i*pi*p/512)
        const float2 w2m = make_float2(w2.y, -w2.x);
        float2 v0 = z[pidx(p)];
        float2 v1 = z[pidx(p + 512)];
        float2 v2 = z[pidx(p + 1024)];
        float2 v3 = z[pidx(p + 1536)];
        float2 t;
        t = cmul(v1, w1); v1 = csub(v0, t); v0 = cadd(v0, t);
        t = cmul(v3, w1); v3 = csub(v2, t); v2 = cadd(v2, t);
        t = cmul(v2, w2);  v2 = csub(v0, t); v0 = cadd(v0, t);
        t = cmul(v3, w2m); v3 = csub(v1, t); v1 = cadd(v1, t);
        // owner-private slots (same as this thread's own reads): race-free
        z[pidx(p + 1024)] = v2;                   // X[p+1024]
        z[pidx(p + 1536)] = v3;                   // X[p+1536]
        V0[itq] = v0; V1[itq] = v1; V2[itq] = v2;
    }
    __syncthreads();

    // ---- fused conjugate-symmetry epilogue: rows k=tid+{0,256,512,768} ----
    // X[1024..2047] are all stashed: item p stashed X[p+1024], X[p+1536].
    const size_t rbase = ((size_t)b * NBINS + (size_t)tid) * NFRAMES + (size_t)f0;
    const size_t rowS  = (size_t)256 * NFRAMES;
    // k = tid: zk = X[tid], zr = X[2048-tid] (tid==0: zr = X[0])
    const float2 zr1 = (tid == 0) ? V0[0] : z[pidx(2048 - tid)];
    store_row2(outr + rbase, outi + rbase, V0[0], zr1);
    // k = tid+256: zr = X[1792-tid]
    store_row2(outr + rbase + rowS, outi + rbase + rowS, V0[1], z[pidx(1792 - tid)]);
    // k = tid+512: zr = X[1536-tid]
    store_row2(outr + rbase + 2 * rowS, outi + rbase + 2 * rowS, V1[0], z[pidx(1536 - tid)]);
    // k = tid+768: zr = X[1280-tid]
    store_row2(outr + rbase + 3 * rowS, outi + rbase + 3 * rowS, V1[1], z[pidx(1280 - tid)]);
    if (tid == 0) {
        // k = 1024: zk = zr = X[1024]
        store_row2(outr + rbase + 4 * rowS, outi + rbase + 4 * rowS, V2[0], V2[0]);
    }
}

extern "C" void kernel_launch(void* const* d_in, const int* in_sizes, int n_in,
                              void* d_out, int out_size, void* d_ws, size_t ws_size,
                              hipStream_t stream) {
    const float* x      = (const float*)d_in[0];
    const float* window = (const float*)d_in[1];
    float* out          = (float*)d_out;

    dim3 grid(4112);   // 16 tail (first) + 4096 main; d_ws deliberately unused
    stft_one<<<grid, 256, 0, stream>>>(x, window, out);
}

// Round 11
// 103.535 us; speedup vs baseline: 1.1572x; 1.1572x over previous
//
#include <hip/hip_runtime.h>

// STFT: x[16, 262144] fp32, Hann 2048, hop 512, reflect pad 1024.
// Output: real[16,1025,513] ++ imag[16,1025,513], fp32.
//
// Round 18: revert to R15 (verified best: 42.7 us kernel dispatch) + drop the
// two inter-trip barriers. R17's 8-blocks/CU probe regressed (43 -> 54.6,
// occupancy did not rise); both directions of the residency lever are now
// measured and 4 blocks x 512 threads is the optimum. This round is R15
// bit-identical except:
//  - Trips 1-3 are wave-local in data (wave w = plane tid>>8, chunk
//    (tid>>6)&3; each octet trip touches only that 512-pt chunk — proven in
//    R10, which ran correct with exactly this fence). The two inter-trip
//    __syncthreads() become wave-local s_waitcnt lgkmcnt(0) + sched_barrier.
//    Block-wide barriers 5 -> 3 (load->trip1, trip3->quad, quad->epi remain:
//    genuinely cross-chunk/cross-wave).
//  - Everything else exactly R15: float4 interior loader (refl provably dead
//    for g in [1,126], brev11(4j+u) = brev9(j)+{0,1024,512,1536}[u]), scalar
//    edge loader, shared-sincos quad, R9 epilogue, octet XCD swizzle, tail
//    blocks first, 512 thr / 2 planes / 33.8 KB LDS / 4 blocks/CU.

#define N_FFT   2048
#define LOG2N   11
#define HOP     512
#define PADL    1024
#define NBINS   1025
#define NFRAMES 513
#define NBATCH  16
#define TLEN    262144

#define HALF_OUT ((size_t)NBATCH * NBINS * NFRAMES)   // 8,413,200 floats per plane

// wave-local fence: my LDS ops done & visible to my own lanes; compiler must
// not hoist the following LDS ops above it (guide rule: inline waitcnt needs
// a sched_barrier fence).
#define WFENCE() do { \
    asm volatile("s_waitcnt lgkmcnt(0)" ::: "memory"); \
    __builtin_amdgcn_sched_barrier(0); \
} while (0)

__device__ __forceinline__ int pidx(int a) { return a + (a >> 5); }

__device__ __forceinline__ int refl(int j) {
    if (j < 0)          j = -j;
    else if (j >= TLEN) j = 2 * TLEN - 2 - j;
    return j;
}

__device__ __forceinline__ int brev11(int n) {
    return (int)(__brev((unsigned)n) >> 21);
}

__device__ __forceinline__ float2 cmul(float2 a, float2 w) {
    return make_float2(fmaf(a.x, w.x, -a.y * w.y), fmaf(a.x, w.y, a.y * w.x));
}
__device__ __forceinline__ float2 cadd(float2 a, float2 b) {
    return make_float2(a.x + b.x, a.y + b.y);
}
__device__ __forceinline__ float2 csub(float2 a, float2 b) {
    return make_float2(a.x - b.x, a.y - b.y);
}
__device__ __forceinline__ float2 csqr(float2 w) {
    return make_float2(fmaf(w.x, w.x, -w.y * w.y), 2.0f * w.x * w.y);
}

// Three DIT stages (halves H, 2H, 4H) on points base + m*H, m=0..7, in registers.
template <int H, int L2H>
__device__ __forceinline__ void octet_pass(float2* __restrict__ zc, int q) {
    const int p    = q & (H - 1);
    const int base = ((q >> L2H) << (L2H + 3)) + p;
    int ia[8];
#pragma unroll
    for (int m = 0; m < 8; ++m) ia[m] = pidx(base + m * H);
    float2 v0 = zc[ia[0]], v1 = zc[ia[1]], v2 = zc[ia[2]], v3 = zc[ia[3]];
    float2 v4 = zc[ia[4]], v5 = zc[ia[5]], v6 = zc[ia[6]], v7 = zc[ia[7]];

    float2 w1, w2, w3;
    if (H == 1) {
        w3 = make_float2(1.0f, 0.0f); w2 = w3; w1 = w3;   // p==0 always
    } else {
        float s, c;
        __sincosf((float)p * (-3.14159265358979323846f / (4.0f * (float)H)), &s, &c);
        w3 = make_float2(c, s);
        w2 = csqr(w3);
        w1 = csqr(w2);
    }

    float2 t;
    // stage A (half=H): pairs (0,1)(2,3)(4,5)(6,7), all twiddle w1
    t = cmul(v1, w1); v1 = csub(v0, t); v0 = cadd(v0, t);
    t = cmul(v3, w1); v3 = csub(v2, t); v2 = cadd(v2, t);
    t = cmul(v5, w1); v5 = csub(v4, t); v4 = cadd(v4, t);
    t = cmul(v7, w1); v7 = csub(v6, t); v6 = cadd(v6, t);
    // stage B (half=2H): pairs (0,2)(4,6) w2 ; (1,3)(5,7) -i*w2
    const float2 w2m = make_float2(w2.y, -w2.x);
    t = cmul(v2, w2);  v2 = csub(v0, t); v0 = cadd(v0, t);
    t = cmul(v3, w2m); v3 = csub(v1, t); v1 = cadd(v1, t);
    t = cmul(v6, w2);  v6 = csub(v4, t); v4 = cadd(v4, t);
    t = cmul(v7, w2m); v7 = csub(v5, t); v5 = cadd(v5, t);
    // stage C (half=4H): pairs (0,4) w3 ; (1,5) w3*e^{-i pi/4} ; (2,6) -i*w3 ; (3,7) -i*w3*e^{-i pi/4}
    const float R = 0.70710678118654752f;
    const float2 w3o  = make_float2((w3.x + w3.y) * R, (w3.y - w3.x) * R);
    const float2 w3m  = make_float2(w3.y, -w3.x);
    const float2 w3mo = make_float2(w3o.y, -w3o.x);
    t = cmul(v4, w3);   v4 = csub(v0, t); v0 = cadd(v0, t);
    t = cmul(v5, w3o);  v5 = csub(v1, t); v1 = cadd(v1, t);
    t = cmul(v6, w3m);  v6 = csub(v2, t); v2 = cadd(v2, t);
    t = cmul(v7, w3mo); v7 = csub(v3, t); v3 = cadd(v3, t);

    zc[ia[0]] = v0; zc[ia[1]] = v1; zc[ia[2]] = v2; zc[ia[3]] = v3;
    zc[ia[4]] = v4; zc[ia[5]] = v5; zc[ia[6]] = v6; zc[ia[7]] = v7;
}

// Radix-4 quad item (stages 10-11, h=512), twiddles precomputed by caller.
__device__ __forceinline__ void quad_core(float2* __restrict__ zc, int p,
                                          float2 w1, float2 w2, float2 w2m) {
    const int i0 = pidx(p), i1 = pidx(p + 512), i2 = pidx(p + 1024), i3 = pidx(p + 1536);
    float2 v0 = zc[i0], v1 = zc[i1], v2 = zc[i2], v3 = zc[i3];
    float2 t;
    t = cmul(v1, w1); v1 = csub(v0, t); v0 = cadd(v0, t);
    t = cmul(v3, w1); v3 = csub(v2, t); v2 = cadd(v2, t);
    t = cmul(v2, w2);  v2 = csub(v0, t); v0 = cadd(v0, t);
    t = cmul(v3, w2m); v3 = csub(v1, t); v1 = cadd(v1, t);
    zc[i0] = v0; zc[i1] = v1; zc[i2] = v2; zc[i3] = v3;
}

__global__ __launch_bounds__(512, 8) void stft_one(
    const float* __restrict__ x,
    const float* __restrict__ window,
    float* __restrict__ out)
{
    __shared__ float2 z[2][2113];     // 33,808 B -> 4 blocks/CU

    const int d   = blockIdx.x;
    const int tid = threadIdx.x;
    float* __restrict__ outr = out;
    float* __restrict__ outi = out + HALF_OUT;

    // ---------------- tail blocks: frame 512 of batch d, run first ----------
    if (d < NBATCH) {
        const int b = d;
        const float* xb = x + (size_t)b * TLEN;
        const int a0 = 512 * HOP - PADL;
#pragma unroll
        for (int it = 0; it < 4; ++it) {
            const int n = tid + it * 512;
            const float w  = window[n];
            const float va = xb[refl(a0 + n)] * w;
            const float vb = xb[refl(a0 + HOP + n)] * w;   // phantom frame, unused
            z[0][pidx(brev11(n))] = make_float2(va, vb);
        }
        __syncthreads();
        if (tid < 256) octet_pass<1, 0>(z[0], tid);
        __syncthreads();
        if (tid < 256) octet_pass<8, 3>(z[0], tid);
        __syncthreads();
        if (tid < 256) octet_pass<64, 6>(z[0], tid);
        __syncthreads();
        {
            float s, cc;
            __sincosf((float)tid * (-3.14159265358979323846f / 1024.0f), &s, &cc);
            const float2 w2  = make_float2(cc, s);
            const float2 w1  = csqr(w2);
            const float2 w2m = make_float2(w2.y, -w2.x);
            quad_core(z[0], tid, w1, w2, w2m);
        }
        __syncthreads();
#pragma unroll
        for (int it = 0; it < 3; ++it) {
            const int k = tid + it * 512;
            if (k < NBINS) {
                const int km = (N_FFT - k) & (N_FFT - 1);
                const float2 zk = z[0][pidx(k)];
                const float2 zr = z[0][pidx(km)];
                const size_t o = ((size_t)b * NBINS + (size_t)k) * NFRAMES + 512;
                outr[o] = 0.5f * (zk.x + zr.x);
                outi[o] = 0.5f * (zk.y - zr.y);
            }
        }
        return;
    }

    // ---------------- main blocks ----------------
    // XCD swizzle (R9): octets of consecutive g (one 128 B output-line span)
    // get ids differing by 8 (same XCD) in adjacent slots (co-resident).
    const int m    = d - NBATCH;                  // [0,2048)
    const int xcd  = m & 7;
    const int slot = m >> 3;                      // [0,256)
    const int O    = (slot >> 3) * 8 + xcd;       // octet id [0,256)
    const int L    = O * 8 + (slot & 7);          // logical block [0,2048)
    const int b    = L >> 7;
    const int g    = L & 127;
    const int f0   = g * 4;

    const float* xb = x + (size_t)b * TLEN;

    // ---- load 4 windowed frames (2 planes), bit-reversed ----
    if (g >= 1 && g <= 126) {
        // interior: refl() dead (span [1024, 260607]); all 16B-aligned.
#pragma unroll
        for (int it = 0; it < 2; ++it) {
            const int idx = tid + it * 512;       // [0,1024)
            const int c   = idx >> 9;
            const int j   = idx & 511;
            const int n0  = j << 2;
            const int a0  = (f0 + 2 * c) * HOP - PADL;
            const float4 w4 = *reinterpret_cast<const float4*>(&window[n0]);
            const float4 a4 = *reinterpret_cast<const float4*>(&xb[a0 + n0]);
            const float4 b4 = *reinterpret_cast<const float4*>(&xb[a0 + HOP + n0]);
            const int r0 = (int)(__brev((unsigned)j) >> 23);   // brev9(j)
            // brev11(4j+u) = brev9(j) + {0,1024,512,1536}[u]
            z[c][pidx(r0)]        = make_float2(a4.x * w4.x, b4.x * w4.x);
            z[c][pidx(r0 + 1024)] = make_float2(a4.y * w4.y, b4.y * w4.y);
            z[c][pidx(r0 + 512)]  = make_float2(a4.z * w4.z, b4.z * w4.z);
            z[c][pidx(r0 + 1536)] = make_float2(a4.w * w4.w, b4.w * w4.w);
        }
    } else {
        // edge blocks (g==0, g==127): scalar refl path (R9 loader)
#pragma unroll
        for (int it = 0; it < 8; ++it) {
            const int idx = tid + it * 512;       // [0,4096)
            const int c   = idx >> 11;
            const int n   = idx & 2047;
            const int fa  = f0 + 2 * c;
            const float w  = window[n];
            const float va = xb[refl(fa * HOP - PADL + n)] * w;
            const float vb = xb[refl((fa + 1) * HOP - PADL + n)] * w;
            z[c][pidx(brev11(n))] = make_float2(va, vb);
        }
    }
    __syncthreads();

    // ---- stages 1-9: three radix-8 register trips ----
    // Wave-local in data (wave w: plane tid>>8, chunk (tid>>6)&3 — each trip
    // touches only that 512-pt chunk), so inter-trip sync is wave-local.
    {
        const int c = tid >> 8, q = tid & 255;
        octet_pass<1, 0>(z[c], q);  WFENCE();
        octet_pass<8, 3>(z[c], q);  WFENCE();
        octet_pass<64, 6>(z[c], q); __syncthreads();   // quad crosses chunks
    }

    // ---- stages 10-11: radix-4 quad pass (h=512), twiddles shared ----
    {
        const int p = tid;                        // [0,512)
        float s, cc;
        __sincosf((float)p * (-3.14159265358979323846f / 1024.0f), &s, &cc);
        const float2 w2  = make_float2(cc, s);    // exp(-i*pi*p/1024)
        const float2 w1  = csqr(w2);              // exp(-i*pi*p/512)
        const float2 w2m = make_float2(w2.y, -w2.x);
        quad_core(z[0], p, w1, w2, w2m);
        quad_core(z[1], p, w1, w2, w2m);
    }
    __syncthreads();

    // ---- unpack + direct write: 16 B chunk per k-row ----
#pragma unroll
    for (int it = 0; it < 3; ++it) {
        const int k = tid + it * 512;
        if (k < NBINS) {
            const int km = (N_FFT - k) & (N_FFT - 1);
            const float2 zk0 = z[0][pidx(k)];
            const float2 zr0 = z[0][pidx(km)];
            const float2 zk1 = z[1][pidx(k)];
            const float2 zr1 = z[1][pidx(km)];
            const size_t o = ((size_t)b * NBINS + (size_t)k) * NFRAMES + (size_t)f0;
            outr[o + 0] = 0.5f * (zk0.x + zr0.x);   // even frame re
            outr[o + 1] = 0.5f * (zk0.y + zr0.y);   // odd frame re
            outr[o + 2] = 0.5f * (zk1.x + zr1.x);
            outr[o + 3] = 0.5f * (zk1.y + zr1.y);
            outi[o + 0] = 0.5f * (zk0.y - zr0.y);   // even frame im
            outi[o + 1] = 0.5f * (zr0.x - zk0.x);   // odd frame im
            outi[o + 2] = 0.5f * (zk1.y - zr1.y);
            outi[o + 3] = 0.5f * (zr1.x - zk1.x);
        }
    }
}

extern "C" void kernel_launch(void* const* d_in, const int* in_sizes, int n_in,
                              void* d_out, int out_size, void* d_ws, size_t ws_size,
                              hipStream_t stream) {
    const float* x      = (const float*)d_in[0];
    const float* window = (const float*)d_in[1];
    float* out          = (float*)d_out;

    dim3 grid(2064);   // 16 tail (first) + 2048 main; d_ws deliberately unused
    stft_one<<<grid, 512, 0, stream>>>(x, window, out);
}